// Round 13
// baseline (201.961 us; speedup 1.0000x reference)
//
#include <hip/hip_runtime.h>

// Problem constants (B=2, S=2048, D=1024, H=16, HD=64). fp32 in / fp32 out.
#define NB 2
#define NS 2048
#define ND 1024
#define NH 16
#define NHD 64
#define QLD (3 * ND)   // qkv workspace row stride in elements = 3072
#define PADP 72        // Ps row stride (u16); 144 B = 16B-aligned rows

typedef unsigned short u16;
typedef __attribute__((ext_vector_type(8))) short short8;   // 8 x bf16 (4 VGPRs)
typedef __attribute__((ext_vector_type(4))) float f32x4;

__device__ __forceinline__ u16 f2b(float f) {
    unsigned int x = __float_as_uint(f);
    return (u16)((x + 0x7fffu + ((x >> 16) & 1u)) >> 16);  // RNE
}

// v_cvt_pk_bf16_f32: low16 = bf16(lo), high16 = bf16(hi), RNE.
__device__ __forceinline__ unsigned int cvtpk(float lo, float hi) {
    unsigned int r;
    asm("v_cvt_pk_bf16_f32 %0, %1, %2" : "=v"(r) : "v"(lo), "v"(hi));
    return r;
}

// 16B-chunk swizzle for Vt: 8-way bank spread on both the write lanes
// (d = 4*vtx+i) and the read lanes (d = dg*16+col). R7/R8-verified.
__device__ __forceinline__ int swz8(int d) {
    return ((d >> 1) ^ (d >> 3)) & 7;
}

// ---------------------------------------------------------------------------
// Fused prep: x fp32->bf16 cast + both weight transposes (W[K,N] fp32 ->
// WT[N,K] bf16). One launch instead of three.
__global__ __launch_bounds__(256) void prep(
    const float* __restrict__ x, u16* __restrict__ x_bf,
    const float* __restrict__ Wqkv, u16* __restrict__ WqkvT,
    const float* __restrict__ Wo, u16* __restrict__ WoT)
{
    __shared__ u16 Ts[64 * 72];
    const int bid = blockIdx.x;
    const int t = threadIdx.x;

    if (bid < 2048) {                    // convert x: 4096*1024 elems
        const int i = (bid * 256 + t) * 8;
        float4 a = *(const float4*)(x + i);
        float4 b = *(const float4*)(x + i + 4);
        *(ushort4*)(x_bf + i)     = make_ushort4(f2b(a.x), f2b(a.y), f2b(a.z), f2b(a.w));
        *(ushort4*)(x_bf + i + 4) = make_ushort4(f2b(b.x), f2b(b.y), f2b(b.z), f2b(b.w));
        return;
    }

    const float* W; u16* WT; int N, bx, by;
    if (bid < 2048 + 768) {              // W_qkv: K=1024, N=3072 -> 48x16 tiles
        const int r = bid - 2048;
        W = Wqkv; WT = WqkvT; N = QLD; bx = r % 48; by = r / 48;
    } else {                             // W_o: K=1024, N=1024 -> 16x16 tiles
        const int r = bid - 2816;
        W = Wo; WT = WoT; N = ND; bx = r & 15; by = r >> 4;
    }
    const int K = ND;
    const int k0 = by << 6, n0 = bx << 6;
    const int rr0 = t >> 4, c = (t & 15) << 2;
    #pragma unroll
    for (int rr = 0; rr < 64; rr += 16) {
        float4 v = *(const float4*)&W[(size_t)(k0 + rr0 + rr) * N + n0 + c];
        Ts[(c + 0) * 72 + rr0 + rr] = f2b(v.x);
        Ts[(c + 1) * 72 + rr0 + rr] = f2b(v.y);
        Ts[(c + 2) * 72 + rr0 + rr] = f2b(v.z);
        Ts[(c + 3) * 72 + rr0 + rr] = f2b(v.w);
    }
    __syncthreads();
    const int n = t >> 2, cc = (t & 3) << 4;
    uint4 a = *(const uint4*)&Ts[n * 72 + cc];
    uint4 b = *(const uint4*)&Ts[n * 72 + cc + 8];
    *(uint4*)&WT[(size_t)(n0 + n) * K + k0 + cc]     = a;
    *(uint4*)&WT[(size_t)(n0 + n) * K + k0 + cc + 8] = b;
}

// ---------------------------------------------------------------------------
// bf16 MFMA GEMM, ONE barrier per K-step, LDS double-buffered (R9).
// C[M,N] = A[M,K] @ BT[N,K]^T + bias[N]; BMxBN tile, 256 threads,
// global_load_lds w=16, XOR swizzle, bijective XCD block swizzle (T1).
// STORE_BF16 pre-scales Q columns ((gc>>6)%3==0) by 0.125*log2(e) -- the
// attn softmax runs in the log2 domain (exp2f, no hidden v_mul). Applied
// in f32 before the bf16 round: one extra half-ulp relative rounding on Q
// (~0.2%), well inside the 5x absmax headroom; R3 proved log2-domain passes.
// Tile search CLOSED (R0/R8/R10/R11): QKV=128x128, Wo=64x64.
template <int BM, int BN, bool STORE_BF16>
__global__ __launch_bounds__(256) void gemm_mfma(
    const u16* __restrict__ A, const u16* __restrict__ BT,
    const float* __restrict__ bias,
    void* __restrict__ C, int M, int N, int K)
{
    constexpr int AIS = BM / 64;
    constexpr int BIS = BN / 64;
    constexpr int MI  = BM / 32;
    constexpr int NJ  = BN / 32;
    __shared__ u16 As[2][BM * 32];
    __shared__ u16 Bs[2][BN * 32];

    const int tid = threadIdx.x;
    const int wave = tid >> 6, lane = tid & 63;
    const int col = lane & 15, quad = lane >> 4;
    const int wm = wave >> 1, wn = wave & 1;

    const int nwgx = gridDim.x;
    const int wg = blockIdx.y * nwgx + blockIdx.x;
    const int cpx = (nwgx * gridDim.y) >> 3;
    const int swz = (wg & 7) * cpx + (wg >> 3);
    const int row0 = (swz / nwgx) * BM, col0 = (swz % nwgx) * BN;

    f32x4 acc[MI][NJ] = {};

    const u16* asrc[AIS];
    u16* adst[2][AIS];
    #pragma unroll
    for (int is = 0; is < AIS; ++is) {
        const int J = is * 256 + wave * 64 + lane;
        const int m = J >> 2;
        const int q = (J & 3) ^ ((m >> 1) & 3);
        asrc[is] = A + (size_t)(row0 + m) * K + q * 8;
        adst[0][is] = &As[0][(size_t)(is * 256 + wave * 64) * 8];
        adst[1][is] = &As[1][(size_t)(is * 256 + wave * 64) * 8];
    }
    const u16* bsrc[BIS];
    u16* bdst[2][BIS];
    #pragma unroll
    for (int is = 0; is < BIS; ++is) {
        const int J = is * 256 + wave * 64 + lane;
        const int m = J >> 2;
        const int q = (J & 3) ^ ((m >> 1) & 3);
        bsrc[is] = BT + (size_t)(col0 + m) * K + q * 8;
        bdst[0][is] = &Bs[0][(size_t)(is * 256 + wave * 64) * 8];
        bdst[1][is] = &Bs[1][(size_t)(is * 256 + wave * 64) * 8];
    }

    auto stage = [&](int buf, int kk) {
        #pragma unroll
        for (int is = 0; is < AIS; ++is)
            __builtin_amdgcn_global_load_lds(
                (const __attribute__((address_space(1))) unsigned int*)(asrc[is] + kk),
                (__attribute__((address_space(3))) unsigned int*)adst[buf][is], 16, 0, 0);
        #pragma unroll
        for (int is = 0; is < BIS; ++is)
            __builtin_amdgcn_global_load_lds(
                (const __attribute__((address_space(1))) unsigned int*)(bsrc[is] + kk),
                (__attribute__((address_space(3))) unsigned int*)bdst[buf][is], 16, 0, 0);
    };

    const int NT = K / 32;
    stage(0, 0);
    __syncthreads();

    for (int t = 0; t < NT; ++t) {
        const int cur = t & 1;
        if (t + 1 < NT) stage(cur ^ 1, (t + 1) * 32);

        short8 af[MI], bf[NJ];
        #pragma unroll
        for (int i = 0; i < MI; ++i) {
            const int m = wm * (BM / 2) + i * 16 + col;
            af[i] = *(const short8*)&As[cur][(m * 4 + (quad ^ ((m >> 1) & 3))) * 8];
        }
        #pragma unroll
        for (int j = 0; j < NJ; ++j) {
            const int n = wn * (BN / 2) + j * 16 + col;
            bf[j] = *(const short8*)&Bs[cur][(n * 4 + (quad ^ ((n >> 1) & 3))) * 8];
        }
        #pragma unroll
        for (int i = 0; i < MI; ++i)
            #pragma unroll
            for (int j = 0; j < NJ; ++j)
                acc[i][j] = __builtin_amdgcn_mfma_f32_16x16x32_bf16(
                    af[i], bf[j], acc[i][j], 0, 0, 0);

        if (t + 1 < NT) __syncthreads();
    }

    #pragma unroll
    for (int j = 0; j < NJ; ++j) {
        const int gc = col0 + wn * (BN / 2) + j * 16 + col;
        // 0.125 * log2(e): softmax runs in log2 domain (exp2f in attn).
        const float qs = (STORE_BF16 && (((gc >> 6) % 3) == 0)) ? 0.18033688f : 1.0f;
        const float bj = bias[gc];
        #pragma unroll
        for (int i = 0; i < MI; ++i) {
            const int gr = row0 + wm * (BM / 2) + i * 16 + quad * 4;
            #pragma unroll
            for (int r = 0; r < 4; ++r) {
                const float v = (acc[i][j][r] + bj) * qs;
                if (STORE_BF16)
                    ((u16*)C)[(size_t)(gr + r) * N + gc] = f2b(v);
                else
                    ((float*)C)[(size_t)(gr + r) * N + gc] = v;
            }
        }
    }
}

// ---------------------------------------------------------------------------
// MFMA flash attention -- R12 kernel (55.7 us, FETCH 12.4 MB via XCD remap)
// + two serial-chain trims:
// (1) PER-LANE defer-max check: the 2 cross-lane shuffles (~120 cyc LDS-pipe
//     latency each, serial) existed only to feed the T13 threshold test.
//     If every lane's LOCAL 16-value max <= m+THR then the per-query max is
//     too -> test __all(mx_local <= m+THR) first (scalar vote, no cross-lane
//     op); run the 2-shuffle reduce only on failure (first tile + rare).
// (2) log2-domain softmax: Q pre-scaled by 0.125*log2e in the GEMM, exp2f
//     here (deletes the 16 hidden v_mul per process). THR = 8*log2e; the
//     P-bound 2^11.54 = e^8 is unchanged (T13-verified regime).
__global__ __launch_bounds__(256) void attn_kernel(
    const u16* __restrict__ qkv, u16* __restrict__ vals)
{
    __shared__ u16 Ks[2][64 * 64];    // 2 x 8 KB, XOR-swizzled 16B chunks
    __shared__ u16 Vt[2][64 * 64];    // 2 x 8 KB, transposed V, swz8 chunks
    __shared__ u16 Ps[64 * PADP];     // 9 KB, per-wave 16-row strips

    const int tid = threadIdx.x;
    const int wave = tid >> 6, lane = tid & 63;
    const int col = lane & 15, quad = lane >> 4;
    const int raw = blockIdx.x + 16 * blockIdx.y;   // 0..511
    const int bh = (raw & 7) + 8 * (raw >> 7);      // same-bh -> same mod-8 (XCD)
    const int qtA = (raw >> 3) & 15;     // 0..15
    const int qtB = 31 - qtA;            // 16..31
    const int b = bh >> 4, h = bh & 15;
    const size_t base = (size_t)b * NS * QLD + (size_t)h * (3 * NHD);
    const int qloc = wave * 16 + col;    // this lane's query (tile-local)

    int Jrow[2], Jcol[2];
    #pragma unroll
    for (int is = 0; is < 2; ++is) {
        const int J = is * 256 + wave * 64 + lane;
        Jrow[is] = J >> 3;
        Jcol[is] = ((J & 7) ^ (Jrow[is] & 7)) << 3;
    }

    auto stage_tile = [&](int buf, int srow, int coloff) {
        #pragma unroll
        for (int is = 0; is < 2; ++is) {
            __builtin_amdgcn_global_load_lds(
                (const __attribute__((address_space(1))) unsigned int*)
                    (qkv + base + (size_t)(srow + Jrow[is]) * QLD + coloff + Jcol[is]),
                (__attribute__((address_space(3))) unsigned int*)
                    &Ks[buf][(size_t)(is * 256 + wave * 64) * 8], 16, 0, 0);
        }
    };
    auto read_frag = [&](int buf, int row, int half) -> short8 {
        const int blk = row * 8 + ((quad + (half << 2)) ^ (row & 7));
        return *(const short8*)&Ks[buf][blk << 3];
    };

    // V reg-staging lanes: lane loads V[vk0..vk0+3][vd0..vd0+3]
    const int vtx = tid & 15, vty = tid >> 4;
    const int vk0 = vty << 2, vd0 = vtx << 2;
    auto load_vregs = [&](int kt, ushort4* vr) {
        const u16* vsrc = qkv + base + (size_t)(kt * 64 + vk0) * QLD + 2 * NHD + vd0;
        vr[0] = *(const ushort4*)(vsrc);
        vr[1] = *(const ushort4*)(vsrc + QLD);
        vr[2] = *(const ushort4*)(vsrc + 2 * QLD);
        vr[3] = *(const ushort4*)(vsrc + 3 * QLD);
    };
    const int vC = vty >> 1, vS = (vty & 1) << 2;
    auto write_vt = [&](int buf, const ushort4* vr) {
        #pragma unroll
        for (int i = 0; i < 4; ++i) {
            const int d = vd0 + i;
            u16* p = &Vt[buf][d * 64 + ((vC ^ swz8(d)) << 3) + vS];
            *(ushort4*)p = make_ushort4(((const u16*)&vr[0])[i],
                                        ((const u16*)&vr[1])[i],
                                        ((const u16*)&vr[2])[i],
                                        ((const u16*)&vr[3])[i]);
        }
    };

    // ---- prologue: stage Q_A -> Ks[0], Q_B -> Ks[1]; hoist B-fragments ----
    stage_tile(0, qtA * 64, 0);
    stage_tile(1, qtB * 64, 0);
    __syncthreads();
    short8 bqA0 = read_frag(0, qloc, 0), bqA1 = read_frag(0, qloc, 1);
    short8 bqB0 = read_frag(1, qloc, 0), bqB1 = read_frag(1, qloc, 1);
    __syncthreads();                     // Q reads done before K(0) overwrites

    f32x4 accA[4] = {}, accB[4] = {};
    float mA = -1e30f, lA = 0.f, mB = -1e30f, lB = 0.f;  // l: per-lane partials

    const float THR = 11.5416f;          // 8 * log2(e): P bounded by e^8

    auto qk = [&](const short8& b0, const short8& b1,
                  short8 (&kb)[4][2], f32x4 (&s)[4]) {
        __builtin_amdgcn_s_setprio(1);
        #pragma unroll
        for (int kg = 0; kg < 4; ++kg) {
            s[kg] = __builtin_amdgcn_mfma_f32_16x16x32_bf16(kb[kg][0], b0, s[kg], 0, 0, 0);
            s[kg] = __builtin_amdgcn_mfma_f32_16x16x32_bf16(kb[kg][1], b1, s[kg], 0, 0, 0);
        }
        __builtin_amdgcn_s_setprio(0);
    };

    auto sm = [&](f32x4 (&s)[4], f32x4 (&acc)[4], float& m, float& lsum, bool diag) {
        if (diag) {                      // wave-uniform branch; Q pre-scaled
            #pragma unroll
            for (int kg = 0; kg < 4; ++kg)
                #pragma unroll
                for (int r = 0; r < 4; ++r)
                    if (kg * 16 + quad * 4 + r > qloc) s[kg][r] = -1e30f;
        }
        float mx = -1e30f;
        #pragma unroll
        for (int kg = 0; kg < 4; ++kg)
            mx = fmaxf(mx, fmaxf(fmaxf(s[kg][0], s[kg][1]), fmaxf(s[kg][2], s[kg][3])));
        // Per-lane defer-max: if every lane's LOCAL max is within THR of the
        // (per-query-uniform) running m, the per-query max is too -> skip
        // both the cross-lane reduce AND the rescale. Cold path only on the
        // first tile and rare max growth.
        if (!__all(mx <= m + THR)) {
            mx = fmaxf(mx, __shfl_xor(mx, 16, 64));
            mx = fmaxf(mx, __shfl_xor(mx, 32, 64));
            const float mn = fmaxf(m, mx);
            const float alpha = exp2f(m - mn);
            m = mn;
            lsum *= alpha;               // alpha uniform across quads of a query
            #pragma unroll
            for (int dg = 0; dg < 4; ++dg)
                #pragma unroll
                for (int r = 0; r < 4; ++r) acc[dg][r] *= alpha;
        }
        float psum = 0.f;
        #pragma unroll
        for (int kg = 0; kg < 4; ++kg) {
            float p0 = exp2f(s[kg][0] - m);
            float p1 = exp2f(s[kg][1] - m);
            float p2 = exp2f(s[kg][2] - m);
            float p3 = exp2f(s[kg][3] - m);
            psum += (p0 + p1) + (p2 + p3);
            uint2 w;
            w.x = cvtpk(p0, p1);
            w.y = cvtpk(p2, p3);
            *(uint2*)&Ps[qloc * PADP + kg * 16 + quad * 4] = w;
        }
        lsum += psum;                    // cross-lane reduce deferred to epilogue
    };

    auto pv = [&](short8 (&vb)[4][2], f32x4 (&acc)[4]) {
        short8 pb0 = *(const short8*)&Ps[qloc * PADP + quad * 8];
        short8 pb1 = *(const short8*)&Ps[qloc * PADP + 32 + quad * 8];
        __builtin_amdgcn_s_setprio(1);
        #pragma unroll
        for (int dg = 0; dg < 4; ++dg) {
            acc[dg] = __builtin_amdgcn_mfma_f32_16x16x32_bf16(vb[dg][0], pb0, acc[dg], 0, 0, 0);
            acc[dg] = __builtin_amdgcn_mfma_f32_16x16x32_bf16(vb[dg][1], pb1, acc[dg], 0, 0, 0);
        }
        __builtin_amdgcn_s_setprio(0);
    };

    // ---- software pipeline: ONE barrier per phase ----
    ushort4 vr[4];
    stage_tile(0, 0, NHD);               // K(0) -> Ks[0]
    load_vregs(0, vr);
    write_vt(0, vr);                     // Vt[0]; no reader before first barrier

    for (int kt = 0; kt <= qtB; ++kt) {
        const int cur = kt & 1, nxt = cur ^ 1;
        __syncthreads();
        if (kt < qtB) {
            stage_tile(nxt, (kt + 1) * 64, NHD);  // in flight during compute
            load_vregs(kt + 1, vr);               // consumed by write_vt below
        }

        // read K/V fragments once, reuse for both q-tiles
        short8 kb[4][2], vb[4][2];
        #pragma unroll
        for (int kg = 0; kg < 4; ++kg) {
            kb[kg][0] = read_frag(cur, kg * 16 + col, 0);
            kb[kg][1] = read_frag(cur, kg * 16 + col, 1);
        }
        #pragma unroll
        for (int dg = 0; dg < 4; ++dg) {
            const int n = dg * 16 + col;
            #pragma unroll
            for (int c = 0; c < 2; ++c)
                vb[dg][c] = *(const short8*)
                    &Vt[cur][n * 64 + (((4 * c + quad) ^ swz8(n)) << 3)];
        }

        {
            f32x4 s[4] = {};
            qk(bqB0, bqB1, kb, s);
            sm(s, accB, mB, lB, kt == qtB);
            pv(vb, accB);
        }
        if (kt <= qtA) {
            f32x4 s[4] = {};
            qk(bqA0, bqA1, kb, s);
            sm(s, accA, mA, lA, kt == qtA);
            pv(vb, accA);
        }

        if (kt < qtB) write_vt(nxt, vr); // write-late: loads aged thru compute
    }

    // ---- epilogue: O^T rows d = dg*16 + quad*4 + r, query qloc ----
    {
        float l1 = lA + __shfl_xor(lA, 16, 64);
        const float inv = 1.f / (l1 + __shfl_xor(l1, 32, 64));
        const size_t rowoff = ((size_t)b * NS + qtA * 64 + qloc) * ND + h * NHD;
        #pragma unroll
        for (int dg = 0; dg < 4; ++dg) {
            uint2 o;
            o.x = cvtpk(accA[dg][0] * inv, accA[dg][1] * inv);
            o.y = cvtpk(accA[dg][2] * inv, accA[dg][3] * inv);
            *(uint2*)(vals + rowoff + dg * 16 + quad * 4) = o;
        }
    }
    {
        float l1 = lB + __shfl_xor(lB, 16, 64);
        const float inv = 1.f / (l1 + __shfl_xor(l1, 32, 64));
        const size_t rowoff = ((size_t)b * NS + qtB * 64 + qloc) * ND + h * NHD;
        #pragma unroll
        for (int dg = 0; dg < 4; ++dg) {
            uint2 o;
            o.x = cvtpk(accB[dg][0] * inv, accB[dg][1] * inv);
            o.y = cvtpk(accB[dg][2] * inv, accB[dg][3] * inv);
            *(uint2*)(vals + rowoff + dg * 16 + quad * 4) = o;
        }
    }
}

extern "C" void kernel_launch(void* const* d_in, const int* in_sizes, int n_in,
                              void* d_out, int out_size, void* d_ws, size_t ws_size,
                              hipStream_t stream)
{
    // inputs: x, mask(unused), W_qkv, b_qkv, W_o, b_o  -- all fp32
    const float* x    = (const float*)d_in[0];
    const float* Wqkv = (const float*)d_in[2];
    const float* bqkv = (const float*)d_in[3];
    const float* Wo   = (const float*)d_in[4];
    const float* bo   = (const float*)d_in[5];
    float* out = (float*)d_out;

    u16* x_bf   = (u16*)d_ws;                       //  4096*1024
    u16* WqkvT  = x_bf   + (size_t)4096 * 1024;     //  3072*1024  [N,K]
    u16* WoT    = WqkvT  + (size_t)3072 * 1024;     //  1024*1024  [N,K]
    u16* qkv    = WoT    + (size_t)1024 * 1024;     //  4096*3072
    u16* vals   = qkv    + (size_t)4096 * 3072;     //  4096*1024

    const int M = NB * NS;  // 4096

    prep<<<dim3(2048 + 768 + 256), dim3(256), 0, stream>>>(
        x, x_bf, Wqkv, WqkvT, Wo, WoT);

    gemm_mfma<128, 128, true><<<dim3(QLD / 128, M / 128), dim3(256), 0, stream>>>(
        x_bf, WqkvT, bqkv, qkv, M, QLD, ND);
    attn_kernel<<<dim3(16, NB * NH), dim3(256), 0, stream>>>(qkv, vals);
    gemm_mfma<64, 64, false><<<dim3(ND / 64, M / 64), dim3(256), 0, stream>>>(
        vals, WoT, bo, out, M, ND, ND);
}

// Round 14
// 193.041 us; speedup vs baseline: 1.0462x; 1.0462x over previous
//
#include <hip/hip_runtime.h>

// Problem constants (B=2, S=2048, D=1024, H=16, HD=64). fp32 in / fp32 out.
#define NB 2
#define NS 2048
#define ND 1024
#define NH 16
#define NHD 64
#define QLD (3 * ND)   // qkv workspace row stride in elements = 3072
#define PADP 72        // Ps row stride (u16); 144 B = 16B-aligned rows

typedef unsigned short u16;
typedef __attribute__((ext_vector_type(8))) short short8;   // 8 x bf16 (4 VGPRs)
typedef __attribute__((ext_vector_type(4))) float f32x4;

__device__ __forceinline__ u16 f2b(float f) {
    unsigned int x = __float_as_uint(f);
    return (u16)((x + 0x7fffu + ((x >> 16) & 1u)) >> 16);  // RNE
}

// v_cvt_pk_bf16_f32: low16 = bf16(lo), high16 = bf16(hi), RNE.
__device__ __forceinline__ unsigned int cvtpk(float lo, float hi) {
    unsigned int r;
    asm("v_cvt_pk_bf16_f32 %0, %1, %2" : "=v"(r) : "v"(lo), "v"(hi));
    return r;
}

// Fast 2^x: single v_exp_f32 (D = 2^S0). R13 lesson: libm exp2f lowers to
// the PRECISE __ocml_exp2_f32 multi-instruction path (VALUBusy 42->51, +4.4
// us); __builtin_amdgcn_exp2f emits the bare HW instruction -- the same one
// __expf uses internally, minus __expf's extra v_mul by log2e.
__device__ __forceinline__ float fexp2(float x) {
    return __builtin_amdgcn_exp2f(x);
}

// 16B-chunk swizzle for Vt: 8-way bank spread on both the write lanes
// (d = 4*vtx+i) and the read lanes (d = dg*16+col). R7/R8-verified.
__device__ __forceinline__ int swz8(int d) {
    return ((d >> 1) ^ (d >> 3)) & 7;
}

// ---------------------------------------------------------------------------
// Fused prep: x fp32->bf16 cast + both weight transposes (W[K,N] fp32 ->
// WT[N,K] bf16). One launch instead of three.
__global__ __launch_bounds__(256) void prep(
    const float* __restrict__ x, u16* __restrict__ x_bf,
    const float* __restrict__ Wqkv, u16* __restrict__ WqkvT,
    const float* __restrict__ Wo, u16* __restrict__ WoT)
{
    __shared__ u16 Ts[64 * 72];
    const int bid = blockIdx.x;
    const int t = threadIdx.x;

    if (bid < 2048) {                    // convert x: 4096*1024 elems
        const int i = (bid * 256 + t) * 8;
        float4 a = *(const float4*)(x + i);
        float4 b = *(const float4*)(x + i + 4);
        *(ushort4*)(x_bf + i)     = make_ushort4(f2b(a.x), f2b(a.y), f2b(a.z), f2b(a.w));
        *(ushort4*)(x_bf + i + 4) = make_ushort4(f2b(b.x), f2b(b.y), f2b(b.z), f2b(b.w));
        return;
    }

    const float* W; u16* WT; int N, bx, by;
    if (bid < 2048 + 768) {              // W_qkv: K=1024, N=3072 -> 48x16 tiles
        const int r = bid - 2048;
        W = Wqkv; WT = WqkvT; N = QLD; bx = r % 48; by = r / 48;
    } else {                             // W_o: K=1024, N=1024 -> 16x16 tiles
        const int r = bid - 2816;
        W = Wo; WT = WoT; N = ND; bx = r & 15; by = r >> 4;
    }
    const int K = ND;
    const int k0 = by << 6, n0 = bx << 6;
    const int rr0 = t >> 4, c = (t & 15) << 2;
    #pragma unroll
    for (int rr = 0; rr < 64; rr += 16) {
        float4 v = *(const float4*)&W[(size_t)(k0 + rr0 + rr) * N + n0 + c];
        Ts[(c + 0) * 72 + rr0 + rr] = f2b(v.x);
        Ts[(c + 1) * 72 + rr0 + rr] = f2b(v.y);
        Ts[(c + 2) * 72 + rr0 + rr] = f2b(v.z);
        Ts[(c + 3) * 72 + rr0 + rr] = f2b(v.w);
    }
    __syncthreads();
    const int n = t >> 2, cc = (t & 3) << 4;
    uint4 a = *(const uint4*)&Ts[n * 72 + cc];
    uint4 b = *(const uint4*)&Ts[n * 72 + cc + 8];
    *(uint4*)&WT[(size_t)(n0 + n) * K + k0 + cc]     = a;
    *(uint4*)&WT[(size_t)(n0 + n) * K + k0 + cc + 8] = b;
}

// ---------------------------------------------------------------------------
// bf16 MFMA GEMM, ONE barrier per K-step, LDS double-buffered (R9).
// C[M,N] = A[M,K] @ BT[N,K]^T + bias[N]; BMxBN tile, 256 threads,
// global_load_lds w=16, XOR swizzle, bijective XCD block swizzle (T1).
// STORE_BF16 pre-scales Q columns ((gc>>6)%3==0) by 0.125*log2(e) -- the
// attn softmax runs in the log2 domain. Applied in f32 before the bf16
// round (~0.2% extra rounding, inside the 5x absmax headroom).
// Tile search CLOSED (R0/R8/R10/R11): QKV=128x128, Wo=64x64.
template <int BM, int BN, bool STORE_BF16>
__global__ __launch_bounds__(256) void gemm_mfma(
    const u16* __restrict__ A, const u16* __restrict__ BT,
    const float* __restrict__ bias,
    void* __restrict__ C, int M, int N, int K)
{
    constexpr int AIS = BM / 64;
    constexpr int BIS = BN / 64;
    constexpr int MI  = BM / 32;
    constexpr int NJ  = BN / 32;
    __shared__ u16 As[2][BM * 32];
    __shared__ u16 Bs[2][BN * 32];

    const int tid = threadIdx.x;
    const int wave = tid >> 6, lane = tid & 63;
    const int col = lane & 15, quad = lane >> 4;
    const int wm = wave >> 1, wn = wave & 1;

    const int nwgx = gridDim.x;
    const int wg = blockIdx.y * nwgx + blockIdx.x;
    const int cpx = (nwgx * gridDim.y) >> 3;
    const int swz = (wg & 7) * cpx + (wg >> 3);
    const int row0 = (swz / nwgx) * BM, col0 = (swz % nwgx) * BN;

    f32x4 acc[MI][NJ] = {};

    const u16* asrc[AIS];
    u16* adst[2][AIS];
    #pragma unroll
    for (int is = 0; is < AIS; ++is) {
        const int J = is * 256 + wave * 64 + lane;
        const int m = J >> 2;
        const int q = (J & 3) ^ ((m >> 1) & 3);
        asrc[is] = A + (size_t)(row0 + m) * K + q * 8;
        adst[0][is] = &As[0][(size_t)(is * 256 + wave * 64) * 8];
        adst[1][is] = &As[1][(size_t)(is * 256 + wave * 64) * 8];
    }
    const u16* bsrc[BIS];
    u16* bdst[2][BIS];
    #pragma unroll
    for (int is = 0; is < BIS; ++is) {
        const int J = is * 256 + wave * 64 + lane;
        const int m = J >> 2;
        const int q = (J & 3) ^ ((m >> 1) & 3);
        bsrc[is] = BT + (size_t)(col0 + m) * K + q * 8;
        bdst[0][is] = &Bs[0][(size_t)(is * 256 + wave * 64) * 8];
        bdst[1][is] = &Bs[1][(size_t)(is * 256 + wave * 64) * 8];
    }

    auto stage = [&](int buf, int kk) {
        #pragma unroll
        for (int is = 0; is < AIS; ++is)
            __builtin_amdgcn_global_load_lds(
                (const __attribute__((address_space(1))) unsigned int*)(asrc[is] + kk),
                (__attribute__((address_space(3))) unsigned int*)adst[buf][is], 16, 0, 0);
        #pragma unroll
        for (int is = 0; is < BIS; ++is)
            __builtin_amdgcn_global_load_lds(
                (const __attribute__((address_space(1))) unsigned int*)(bsrc[is] + kk),
                (__attribute__((address_space(3))) unsigned int*)bdst[buf][is], 16, 0, 0);
    };

    const int NT = K / 32;
    stage(0, 0);
    __syncthreads();

    for (int t = 0; t < NT; ++t) {
        const int cur = t & 1;
        if (t + 1 < NT) stage(cur ^ 1, (t + 1) * 32);

        short8 af[MI], bf[NJ];
        #pragma unroll
        for (int i = 0; i < MI; ++i) {
            const int m = wm * (BM / 2) + i * 16 + col;
            af[i] = *(const short8*)&As[cur][(m * 4 + (quad ^ ((m >> 1) & 3))) * 8];
        }
        #pragma unroll
        for (int j = 0; j < NJ; ++j) {
            const int n = wn * (BN / 2) + j * 16 + col;
            bf[j] = *(const short8*)&Bs[cur][(n * 4 + (quad ^ ((n >> 1) & 3))) * 8];
        }
        #pragma unroll
        for (int i = 0; i < MI; ++i)
            #pragma unroll
            for (int j = 0; j < NJ; ++j)
                acc[i][j] = __builtin_amdgcn_mfma_f32_16x16x32_bf16(
                    af[i], bf[j], acc[i][j], 0, 0, 0);

        if (t + 1 < NT) __syncthreads();
    }

    #pragma unroll
    for (int j = 0; j < NJ; ++j) {
        const int gc = col0 + wn * (BN / 2) + j * 16 + col;
        // 0.125 * log2(e): softmax runs in log2 domain (v_exp_f32 in attn).
        const float qs = (STORE_BF16 && (((gc >> 6) % 3) == 0)) ? 0.18033688f : 1.0f;
        const float bj = bias[gc];
        #pragma unroll
        for (int i = 0; i < MI; ++i) {
            const int gr = row0 + wm * (BM / 2) + i * 16 + quad * 4;
            #pragma unroll
            for (int r = 0; r < 4; ++r) {
                const float v = (acc[i][j][r] + bj) * qs;
                if (STORE_BF16)
                    ((u16*)C)[(size_t)(gr + r) * N + gc] = f2b(v);
                else
                    ((float*)C)[(size_t)(gr + r) * N + gc] = v;
            }
        }
    }
}

// ---------------------------------------------------------------------------
// MFMA flash attention -- R13 structure with the exp fixed: all exps are
// __builtin_amdgcn_exp2f (bare v_exp_f32). Per-process exp cost ladder:
// R12 = 16x(v_mul+v_exp) -> R13 = 16x slow libm exp2f (REGRESSED, VALUBusy
// 42->51) -> R14 = 16x v_exp only. Keeps R13's per-lane defer-max (skips
// the 2 cross-lane shuffles on the common path) and R12's XCD remap
// (FETCH 64->12.4 MB verified).
__global__ __launch_bounds__(256) void attn_kernel(
    const u16* __restrict__ qkv, u16* __restrict__ vals)
{
    __shared__ u16 Ks[2][64 * 64];    // 2 x 8 KB, XOR-swizzled 16B chunks
    __shared__ u16 Vt[2][64 * 64];    // 2 x 8 KB, transposed V, swz8 chunks
    __shared__ u16 Ps[64 * PADP];     // 9 KB, per-wave 16-row strips

    const int tid = threadIdx.x;
    const int wave = tid >> 6, lane = tid & 63;
    const int col = lane & 15, quad = lane >> 4;
    const int raw = blockIdx.x + 16 * blockIdx.y;   // 0..511
    const int bh = (raw & 7) + 8 * (raw >> 7);      // same-bh -> same mod-8 (XCD)
    const int qtA = (raw >> 3) & 15;     // 0..15
    const int qtB = 31 - qtA;            // 16..31
    const int b = bh >> 4, h = bh & 15;
    const size_t base = (size_t)b * NS * QLD + (size_t)h * (3 * NHD);
    const int qloc = wave * 16 + col;    // this lane's query (tile-local)

    int Jrow[2], Jcol[2];
    #pragma unroll
    for (int is = 0; is < 2; ++is) {
        const int J = is * 256 + wave * 64 + lane;
        Jrow[is] = J >> 3;
        Jcol[is] = ((J & 7) ^ (Jrow[is] & 7)) << 3;
    }

    auto stage_tile = [&](int buf, int srow, int coloff) {
        #pragma unroll
        for (int is = 0; is < 2; ++is) {
            __builtin_amdgcn_global_load_lds(
                (const __attribute__((address_space(1))) unsigned int*)
                    (qkv + base + (size_t)(srow + Jrow[is]) * QLD + coloff + Jcol[is]),
                (__attribute__((address_space(3))) unsigned int*)
                    &Ks[buf][(size_t)(is * 256 + wave * 64) * 8], 16, 0, 0);
        }
    };
    auto read_frag = [&](int buf, int row, int half) -> short8 {
        const int blk = row * 8 + ((quad + (half << 2)) ^ (row & 7));
        return *(const short8*)&Ks[buf][blk << 3];
    };

    // V reg-staging lanes: lane loads V[vk0..vk0+3][vd0..vd0+3]
    const int vtx = tid & 15, vty = tid >> 4;
    const int vk0 = vty << 2, vd0 = vtx << 2;
    auto load_vregs = [&](int kt, ushort4* vr) {
        const u16* vsrc = qkv + base + (size_t)(kt * 64 + vk0) * QLD + 2 * NHD + vd0;
        vr[0] = *(const ushort4*)(vsrc);
        vr[1] = *(const ushort4*)(vsrc + QLD);
        vr[2] = *(const ushort4*)(vsrc + 2 * QLD);
        vr[3] = *(const ushort4*)(vsrc + 3 * QLD);
    };
    const int vC = vty >> 1, vS = (vty & 1) << 2;
    auto write_vt = [&](int buf, const ushort4* vr) {
        #pragma unroll
        for (int i = 0; i < 4; ++i) {
            const int d = vd0 + i;
            u16* p = &Vt[buf][d * 64 + ((vC ^ swz8(d)) << 3) + vS];
            *(ushort4*)p = make_ushort4(((const u16*)&vr[0])[i],
                                        ((const u16*)&vr[1])[i],
                                        ((const u16*)&vr[2])[i],
                                        ((const u16*)&vr[3])[i]);
        }
    };

    // ---- prologue: stage Q_A -> Ks[0], Q_B -> Ks[1]; hoist B-fragments ----
    stage_tile(0, qtA * 64, 0);
    stage_tile(1, qtB * 64, 0);
    __syncthreads();
    short8 bqA0 = read_frag(0, qloc, 0), bqA1 = read_frag(0, qloc, 1);
    short8 bqB0 = read_frag(1, qloc, 0), bqB1 = read_frag(1, qloc, 1);
    __syncthreads();                     // Q reads done before K(0) overwrites

    f32x4 accA[4] = {}, accB[4] = {};
    float mA = -1e30f, lA = 0.f, mB = -1e30f, lB = 0.f;  // l: per-lane partials

    const float THR = 11.5416f;          // 8 * log2(e): P bounded by e^8

    auto qk = [&](const short8& b0, const short8& b1,
                  short8 (&kb)[4][2], f32x4 (&s)[4]) {
        __builtin_amdgcn_s_setprio(1);
        #pragma unroll
        for (int kg = 0; kg < 4; ++kg) {
            s[kg] = __builtin_amdgcn_mfma_f32_16x16x32_bf16(kb[kg][0], b0, s[kg], 0, 0, 0);
            s[kg] = __builtin_amdgcn_mfma_f32_16x16x32_bf16(kb[kg][1], b1, s[kg], 0, 0, 0);
        }
        __builtin_amdgcn_s_setprio(0);
    };

    auto sm = [&](f32x4 (&s)[4], f32x4 (&acc)[4], float& m, float& lsum, bool diag) {
        if (diag) {                      // wave-uniform branch; Q pre-scaled
            #pragma unroll
            for (int kg = 0; kg < 4; ++kg)
                #pragma unroll
                for (int r = 0; r < 4; ++r)
                    if (kg * 16 + quad * 4 + r > qloc) s[kg][r] = -1e30f;
        }
        float mx = -1e30f;
        #pragma unroll
        for (int kg = 0; kg < 4; ++kg)
            mx = fmaxf(mx, fmaxf(fmaxf(s[kg][0], s[kg][1]), fmaxf(s[kg][2], s[kg][3])));
        // Per-lane defer-max: if every lane's LOCAL max is within THR of the
        // (per-query-uniform) running m, the per-query max is too -> skip
        // the cross-lane reduce AND the rescale. Cold path: first tile +
        // rare max growth.
        if (!__all(mx <= m + THR)) {
            mx = fmaxf(mx, __shfl_xor(mx, 16, 64));
            mx = fmaxf(mx, __shfl_xor(mx, 32, 64));
            const float mn = fmaxf(m, mx);
            const float alpha = fexp2(m - mn);
            m = mn;
            lsum *= alpha;               // alpha uniform across quads of a query
            #pragma unroll
            for (int dg = 0; dg < 4; ++dg)
                #pragma unroll
                for (int r = 0; r < 4; ++r) acc[dg][r] *= alpha;
        }
        float psum = 0.f;
        #pragma unroll
        for (int kg = 0; kg < 4; ++kg) {
            float p0 = fexp2(s[kg][0] - m);
            float p1 = fexp2(s[kg][1] - m);
            float p2 = fexp2(s[kg][2] - m);
            float p3 = fexp2(s[kg][3] - m);
            psum += (p0 + p1) + (p2 + p3);
            uint2 w;
            w.x = cvtpk(p0, p1);
            w.y = cvtpk(p2, p3);
            *(uint2*)&Ps[qloc * PADP + kg * 16 + quad * 4] = w;
        }
        lsum += psum;                    // cross-lane reduce deferred to epilogue
    };

    auto pv = [&](short8 (&vb)[4][2], f32x4 (&acc)[4]) {
        short8 pb0 = *(const short8*)&Ps[qloc * PADP + quad * 8];
        short8 pb1 = *(const short8*)&Ps[qloc * PADP + 32 + quad * 8];
        __builtin_amdgcn_s_setprio(1);
        #pragma unroll
        for (int dg = 0; dg < 4; ++dg) {
            acc[dg] = __builtin_amdgcn_mfma_f32_16x16x32_bf16(vb[dg][0], pb0, acc[dg], 0, 0, 0);
            acc[dg] = __builtin_amdgcn_mfma_f32_16x16x32_bf16(vb[dg][1], pb1, acc[dg], 0, 0, 0);
        }
        __builtin_amdgcn_s_setprio(0);
    };

    // ---- software pipeline: ONE barrier per phase ----
    ushort4 vr[4];
    stage_tile(0, 0, NHD);               // K(0) -> Ks[0]
    load_vregs(0, vr);
    write_vt(0, vr);                     // Vt[0]; no reader before first barrier

    for (int kt = 0; kt <= qtB; ++kt) {
        const int cur = kt & 1, nxt = cur ^ 1;
        __syncthreads();
        if (kt < qtB) {
            stage_tile(nxt, (kt + 1) * 64, NHD);  // in flight during compute
            load_vregs(kt + 1, vr);               // consumed by write_vt below
        }

        // read K/V fragments once, reuse for both q-tiles
        short8 kb[4][2], vb[4][2];
        #pragma unroll
        for (int kg = 0; kg < 4; ++kg) {
            kb[kg][0] = read_frag(cur, kg * 16 + col, 0);
            kb[kg][1] = read_frag(cur, kg * 16 + col, 1);
        }
        #pragma unroll
        for (int dg = 0; dg < 4; ++dg) {
            const int n = dg * 16 + col;
            #pragma unroll
            for (int c = 0; c < 2; ++c)
                vb[dg][c] = *(const short8*)
                    &Vt[cur][n * 64 + (((4 * c + quad) ^ swz8(n)) << 3)];
        }

        {
            f32x4 s[4] = {};
            qk(bqB0, bqB1, kb, s);
            sm(s, accB, mB, lB, kt == qtB);
            pv(vb, accB);
        }
        if (kt <= qtA) {
            f32x4 s[4] = {};
            qk(bqA0, bqA1, kb, s);
            sm(s, accA, mA, lA, kt == qtA);
            pv(vb, accA);
        }

        if (kt < qtB) write_vt(nxt, vr); // write-late: loads aged thru compute
    }

    // ---- epilogue: O^T rows d = dg*16 + quad*4 + r, query qloc ----
    {
        float l1 = lA + __shfl_xor(lA, 16, 64);
        const float inv = 1.f / (l1 + __shfl_xor(l1, 32, 64));
        const size_t rowoff = ((size_t)b * NS + qtA * 64 + qloc) * ND + h * NHD;
        #pragma unroll
        for (int dg = 0; dg < 4; ++dg) {
            uint2 o;
            o.x = cvtpk(accA[dg][0] * inv, accA[dg][1] * inv);
            o.y = cvtpk(accA[dg][2] * inv, accA[dg][3] * inv);
            *(uint2*)(vals + rowoff + dg * 16 + quad * 4) = o;
        }
    }
    {
        float l1 = lB + __shfl_xor(lB, 16, 64);
        const float inv = 1.f / (l1 + __shfl_xor(l1, 32, 64));
        const size_t rowoff = ((size_t)b * NS + qtB * 64 + qloc) * ND + h * NHD;
        #pragma unroll
        for (int dg = 0; dg < 4; ++dg) {
            uint2 o;
            o.x = cvtpk(accB[dg][0] * inv, accB[dg][1] * inv);
            o.y = cvtpk(accB[dg][2] * inv, accB[dg][3] * inv);
            *(uint2*)(vals + rowoff + dg * 16 + quad * 4) = o;
        }
    }
}

extern "C" void kernel_launch(void* const* d_in, const int* in_sizes, int n_in,
                              void* d_out, int out_size, void* d_ws, size_t ws_size,
                              hipStream_t stream)
{
    // inputs: x, mask(unused), W_qkv, b_qkv, W_o, b_o  -- all fp32
    const float* x    = (const float*)d_in[0];
    const float* Wqkv = (const float*)d_in[2];
    const float* bqkv = (const float*)d_in[3];
    const float* Wo   = (const float*)d_in[4];
    const float* bo   = (const float*)d_in[5];
    float* out = (float*)d_out;

    u16* x_bf   = (u16*)d_ws;                       //  4096*1024
    u16* WqkvT  = x_bf   + (size_t)4096 * 1024;     //  3072*1024  [N,K]
    u16* WoT    = WqkvT  + (size_t)3072 * 1024;     //  1024*1024  [N,K]
    u16* qkv    = WoT    + (size_t)1024 * 1024;     //  4096*3072
    u16* vals   = qkv    + (size_t)4096 * 3072;     //  4096*1024

    const int M = NB * NS;  // 4096

    prep<<<dim3(2048 + 768 + 256), dim3(256), 0, stream>>>(
        x, x_bf, Wqkv, WqkvT, Wo, WoT);

    gemm_mfma<128, 128, true><<<dim3(QLD / 128, M / 128), dim3(256), 0, stream>>>(
        x_bf, WqkvT, bqkv, qkv, M, QLD, ND);
    attn_kernel<<<dim3(16, NB * NH), dim3(256), 0, stream>>>(qkv, vals);
    gemm_mfma<64, 64, false><<<dim3(ND / 64, M / 64), dim3(256), 0, stream>>>(
        vals, WoT, bo, out, M, ND, ND);
}